// Round 1
// baseline (1104.795 us; speedup 1.0000x reference)
//
#include <hip/hip_runtime.h>
#include <cstdint>
#include <cstddef>

#define B_ 2
#define S_ 4096
#define T_ 4096
#define D_ 512
#define W_ 128

// ---- fast sigmoid pieces ------------------------------------------------
#if __has_builtin(__builtin_amdgcn_exp2f)
#define EXPSCALE (-1.4426950408889634f)   // fold -log2(e) into ptc, use v_exp_f32 directly
__device__ __forceinline__ float expfn(float x){ return __builtin_amdgcn_exp2f(x); }
#else
#define EXPSCALE (-1.0f)
__device__ __forceinline__ float expfn(float x){ return __expf(x); }
#endif

#if __has_builtin(__builtin_amdgcn_rcpf)
__device__ __forceinline__ float rcpfn(float x){ return __builtin_amdgcn_rcpf(x); }
#else
__device__ __forceinline__ float rcpfn(float x){ return 1.0f / x; }
#endif

__device__ __forceinline__ uint16_t f2bf(float f){
  uint32_t u = __float_as_uint(f);
  u += 0x7FFFu + ((u >> 16) & 1u);        // round-to-nearest-even
  return (uint16_t)(u >> 16);
}

// ---- dtype detector: bf16 low-half has an exponent field, fp32 has mantissa bits
__global__ void detect_k(const uint32_t* __restrict__ src, int* __restrict__ flag){
  int lane = threadIdx.x;
  uint32_t u = src[lane];
  uint32_t e_lo = (u >> 7) & 0xFFu;       // exponent of even bf16 element if bf16 buffer
  bool hit = (e_lo >= 110u && e_lo <= 132u);
  unsigned long long m = __ballot(hit);
  if (lane == 0) *flag = (__popcll(m) >= 32) ? 1 : 0;
}

// ---- convert input (bf16 or fp32) to fp32 workspace ---------------------
__global__ void convert_k(const void* __restrict__ in, float* __restrict__ out,
                          int n, const int* __restrict__ flag){
  bool isbf = (*flag != 0);
  int i = blockIdx.x * blockDim.x + threadIdx.x;
  int stride = gridDim.x * blockDim.x;
  if (isbf){
    const uint16_t* p = (const uint16_t*)in;
    for (; i < n; i += stride) out[i] = __uint_as_float(((uint32_t)p[i]) << 16);
  } else {
    const float* p = (const float*)in;
    for (; i < n; i += stride) out[i] = p[i];
  }
}

// ---- transpose W [128,512] -> WT [512,128] (writes coalesced) -----------
__global__ void transpose_k(const float* __restrict__ a, const float* __restrict__ b,
                            float* __restrict__ at, float* __restrict__ bt){
  const float* in = blockIdx.x ? b : a;
  float* out = blockIdx.x ? bt : at;
  for (int o = threadIdx.x; o < D_ * W_; o += blockDim.x){
    int d = o >> 7, w = o & (W_ - 1);
    out[o] = in[w * D_ + d];
  }
}

union F4 { float4 v; float f[4]; };

// ---- projection: out = x @ W^T, plus lin = proj . wout ------------------
// MODE 0 (source): outA = ps (raw)
// MODE 1 (target): outA = pt*EXPSCALE, outB = pt*w_int
template<int MODE>
__global__ __launch_bounds__(256) void proj_k(const float* __restrict__ x,
        const float* __restrict__ WT, const float* __restrict__ wout,
        const float* __restrict__ wint, float* __restrict__ outA,
        float* __restrict__ outB, float* __restrict__ lin){
  __shared__ float xl[64 * 36];           // [d][r] transposed, pad 36 (16B-aligned rows)
  __shared__ float wl[64 * 128];          // [d][w] natural (WT is pre-transposed)
  int tid = threadIdx.x;
  int tx = tid & 31, ty = tid >> 5;       // tx: 32 w-groups of 4; ty: 8 row-groups of 4
  int rowBase = blockIdx.x * 32;
  float acc[4][4] = {};
  for (int c = 0; c < 8; ++c){
    int d0 = c * 64;
    const float4* wt4 = (const float4*)(WT + (size_t)d0 * W_);
    float4* wl4 = (float4*)wl;
    #pragma unroll
    for (int p = 0; p < 8; ++p){ int q = tid + 256 * p; wl4[q] = wt4[q]; }
    #pragma unroll
    for (int p = 0; p < 2; ++p){
      int q = tid + 256 * p;
      int r = q >> 4, dq = q & 15;
      F4 v; v.v = *(const float4*)(x + (size_t)(rowBase + r) * D_ + d0 + dq * 4);
      xl[(dq*4+0)*36 + r] = v.f[0];
      xl[(dq*4+1)*36 + r] = v.f[1];
      xl[(dq*4+2)*36 + r] = v.f[2];
      xl[(dq*4+3)*36 + r] = v.f[3];
    }
    __syncthreads();
    #pragma unroll 4
    for (int d = 0; d < 64; ++d){
      F4 a, w;
      a.v = *(const float4*)(xl + d * 36 + ty * 4);
      w.v = *(const float4*)(wl + d * 128 + tx * 4);
      #pragma unroll
      for (int i = 0; i < 4; ++i)
        #pragma unroll
        for (int j = 0; j < 4; ++j)
          acc[i][j] = fmaf(a.f[i], w.f[j], acc[i][j]);
    }
    __syncthreads();
  }
  F4 wo; wo.v = *(const float4*)(wout + tx * 4);
  F4 wi; wi.v = make_float4(0.f, 0.f, 0.f, 0.f);
  if (MODE == 1) wi.v = *(const float4*)(wint + tx * 4);
  #pragma unroll
  for (int i = 0; i < 4; ++i){
    int r = rowBase + ty * 4 + i;
    float s = acc[i][0]*wo.f[0] + acc[i][1]*wo.f[1] + acc[i][2]*wo.f[2] + acc[i][3]*wo.f[3];
    #pragma unroll
    for (int off = 16; off >= 1; off >>= 1) s += __shfl_xor(s, off, 32);
    if (tx == 0) lin[r] = s;
    if (MODE == 0){
      float4 o = make_float4(acc[i][0], acc[i][1], acc[i][2], acc[i][3]);
      *(float4*)(outA + (size_t)r * W_ + tx * 4) = o;
    } else {
      float4 oc = make_float4(acc[i][0]*EXPSCALE, acc[i][1]*EXPSCALE,
                              acc[i][2]*EXPSCALE, acc[i][3]*EXPSCALE);
      *(float4*)(outA + (size_t)r * W_ + tx * 4) = oc;
      float4 ow = make_float4(acc[i][0]*wi.f[0], acc[i][1]*wi.f[1],
                              acc[i][2]*wi.f[2], acc[i][3]*wi.f[3]);
      *(float4*)(outB + (size_t)r * W_ + tx * 4) = ow;
    }
  }
}

// ---- main route kernel: 64x64 output tile, 4x4 per thread ---------------
__global__ __launch_bounds__(256, 3) void route_k(const float* __restrict__ ps,
      const float* __restrict__ ptc, const float* __restrict__ ptw,
      const float* __restrict__ slin, const float* __restrict__ tlin,
      const float* __restrict__ biasp, const int* __restrict__ flag,
      void* __restrict__ outv){
  __shared__ float psl[64 * 68];          // [w][s], pad 68 (272B rows, 16B-aligned)
  __shared__ float pcl[64 * 68];          // [w][t]
  __shared__ float pwl[64 * 68];          // [w][t]
  int tid = threadIdx.x;
  int tx = tid & 15, ty = tid >> 4;
  int b = blockIdx.z;
  int sBase = blockIdx.y * 64, tBase = blockIdx.x * 64;
  const float* psp = ps  + ((size_t)b * S_ + sBase) * W_;
  const float* pcp = ptc + ((size_t)b * T_ + tBase) * W_;
  const float* pwp = ptw + ((size_t)b * T_ + tBase) * W_;
  float acc[4][4] = {};
  for (int wc = 0; wc < W_; wc += 64){
    #pragma unroll
    for (int p = 0; p < 4; ++p){
      int q = tid + 256 * p;
      int s = q >> 4, wq = q & 15;
      F4 v1; v1.v = *(const float4*)(psp + (size_t)s * W_ + wc + wq * 4);
      psl[(wq*4+0)*68 + s] = v1.f[0]; psl[(wq*4+1)*68 + s] = v1.f[1];
      psl[(wq*4+2)*68 + s] = v1.f[2]; psl[(wq*4+3)*68 + s] = v1.f[3];
      F4 v2; v2.v = *(const float4*)(pcp + (size_t)s * W_ + wc + wq * 4);
      pcl[(wq*4+0)*68 + s] = v2.f[0]; pcl[(wq*4+1)*68 + s] = v2.f[1];
      pcl[(wq*4+2)*68 + s] = v2.f[2]; pcl[(wq*4+3)*68 + s] = v2.f[3];
      F4 v3; v3.v = *(const float4*)(pwp + (size_t)s * W_ + wc + wq * 4);
      pwl[(wq*4+0)*68 + s] = v3.f[0]; pwl[(wq*4+1)*68 + s] = v3.f[1];
      pwl[(wq*4+2)*68 + s] = v3.f[2]; pwl[(wq*4+3)*68 + s] = v3.f[3];
    }
    __syncthreads();
    #pragma unroll 4
    for (int w = 0; w < 64; ++w){
      F4 a, c, u;
      a.v = *(const float4*)(psl + w * 68 + ty * 4);
      c.v = *(const float4*)(pcl + w * 68 + tx * 4);
      u.v = *(const float4*)(pwl + w * 68 + tx * 4);
      #pragma unroll
      for (int i = 0; i < 4; ++i)
        #pragma unroll
        for (int j = 0; j < 4; ++j){
          float t = a.f[i] * c.f[j];            // = -z*log2(e)   (z = ps*pt)
          float e = expfn(t);                   // = e^{-z}
          float r = rcpfn(1.0f + e);            // = sigmoid(z)
          acc[i][j] = fmaf(a.f[i] * u.f[j], r, acc[i][j]);  // += z*w_int*sigmoid(z)
        }
    }
    __syncthreads();
  }
  float bz = biasp[0];
  F4 tl; tl.v = *(const float4*)(tlin + (size_t)b * T_ + tBase + tx * 4);
  bool isbf = (*flag != 0);
  #pragma unroll
  for (int i = 0; i < 4; ++i){
    int s = sBase + ty * 4 + i;
    float sl = slin[(size_t)b * S_ + s] + bz;
    float o0 = acc[i][0] + sl + tl.f[0];
    float o1 = acc[i][1] + sl + tl.f[1];
    float o2 = acc[i][2] + sl + tl.f[2];
    float o3 = acc[i][3] + sl + tl.f[3];
    size_t idx = ((size_t)b * S_ + s) * T_ + tBase + tx * 4;
    if (isbf){
      ushort4 pk;
      pk.x = f2bf(o0); pk.y = f2bf(o1); pk.z = f2bf(o2); pk.w = f2bf(o3);
      *(ushort4*)((uint16_t*)outv + idx) = pk;
    } else {
      float4 o = make_float4(o0, o1, o2, o3);
      *(float4*)((float*)outv + idx) = o;
    }
  }
}

extern "C" void kernel_launch(void* const* d_in, const int* in_sizes, int n_in,
                              void* d_out, int out_size, void* d_ws, size_t ws_size,
                              hipStream_t stream){
  char* ws = (char*)d_ws;
  size_t off = 0;
  auto alloc = [&](size_t bytes)->char*{
    char* p = ws + off; off += (bytes + 255) & ~(size_t)255; return p;
  };
  int*   flag = (int*)  alloc(4);
  float* srcf = (float*)alloc((size_t)B_*S_*D_*4);
  float* tgtf = (float*)alloc((size_t)B_*T_*D_*4);
  float* Wsf  = (float*)alloc((size_t)W_*D_*4);
  float* Wtf  = (float*)alloc((size_t)W_*D_*4);
  float* wsof = (float*)alloc(W_*4);
  float* wtof = (float*)alloc(W_*4);
  float* wif  = (float*)alloc(W_*4);
  float* bf   = (float*)alloc(4);
  float* WsT  = (float*)alloc((size_t)D_*W_*4);
  float* WtT  = (float*)alloc((size_t)D_*W_*4);
  float* ps   = (float*)alloc((size_t)B_*S_*W_*4);
  float* ptc  = (float*)alloc((size_t)B_*T_*W_*4);
  float* ptw  = (float*)alloc((size_t)B_*T_*W_*4);
  float* slin = (float*)alloc((size_t)B_*S_*4);
  float* tlin = (float*)alloc((size_t)B_*T_*4);

  hipLaunchKernelGGL(detect_k, dim3(1), dim3(64), 0, stream,
                     (const uint32_t*)d_in[0], flag);
  const int nbig = B_*S_*D_;
  hipLaunchKernelGGL(convert_k, dim3(2048), dim3(256), 0, stream, d_in[0], srcf, nbig, flag);
  hipLaunchKernelGGL(convert_k, dim3(2048), dim3(256), 0, stream, d_in[1], tgtf, nbig, flag);
  hipLaunchKernelGGL(convert_k, dim3(256),  dim3(256), 0, stream, d_in[2], Wsf, W_*D_, flag);
  hipLaunchKernelGGL(convert_k, dim3(256),  dim3(256), 0, stream, d_in[3], Wtf, W_*D_, flag);
  hipLaunchKernelGGL(convert_k, dim3(1),    dim3(256), 0, stream, d_in[4], wsof, W_, flag);
  hipLaunchKernelGGL(convert_k, dim3(1),    dim3(256), 0, stream, d_in[5], wtof, W_, flag);
  hipLaunchKernelGGL(convert_k, dim3(1),    dim3(256), 0, stream, d_in[6], wif, W_, flag);
  hipLaunchKernelGGL(convert_k, dim3(1),    dim3(256), 0, stream, d_in[7], bf, 1, flag);
  hipLaunchKernelGGL(transpose_k, dim3(2), dim3(256), 0, stream, Wsf, Wtf, WsT, WtT);
  hipLaunchKernelGGL((proj_k<0>), dim3(B_*S_/32), dim3(256), 0, stream,
                     srcf, WsT, wsof, wif, ps, (float*)nullptr, slin);
  hipLaunchKernelGGL((proj_k<1>), dim3(B_*T_/32), dim3(256), 0, stream,
                     tgtf, WtT, wtof, wif, ptc, ptw, tlin);
  hipLaunchKernelGGL(route_k, dim3(T_/64, S_/64, B_), dim3(256), 0, stream,
                     ps, ptc, ptw, slin, tlin, bf, flag, d_out);
}

// Round 2
// 762.217 us; speedup vs baseline: 1.4494x; 1.4494x over previous
//
#include <hip/hip_runtime.h>
#include <cstdint>
#include <cstddef>

#define B_ 2
#define S_ 4096
#define T_ 4096
#define D_ 512
#define W_ 128

// degree-4 poly in t=z^2 for h(t) = silu(z) - z/2, fit on t in [0, 6.25]
#define A0C (-0.0006958f)
#define A1C (0.2529946f)
#define A2C (-0.0226345f)
#define A3C (0.0022173f)
#define A4C (-0.00011668f)
#define ZCUT 2.5f
#define FIXCAP (4*1024*1024)

typedef __attribute__((ext_vector_type(8))) short bf16x8;
typedef __attribute__((ext_vector_type(4))) float f32x4;

__device__ __forceinline__ uint16_t f2bf(float f){
  uint32_t u = __float_as_uint(f);
  u += 0x7FFFu + ((u >> 16) & 1u);        // round-to-nearest-even
  return (uint16_t)(u >> 16);
}
__device__ __forceinline__ float bf2f(uint16_t h){
  return __uint_as_float(((uint32_t)h) << 16);
}

__device__ __forceinline__ void gl_lds16(const void* g, void* l){
  __builtin_amdgcn_global_load_lds(
      (const __attribute__((address_space(1))) void*)g,
      (__attribute__((address_space(3))) void*)l, 16, 0, 0);
}

// ---- dtype detector: bf16 low-half has an exponent field, fp32 has mantissa bits
__global__ void detect_k(const uint32_t* __restrict__ src, int* __restrict__ flag){
  int lane = threadIdx.x;
  uint32_t u = src[lane];
  uint32_t e_lo = (u >> 7) & 0xFFu;
  bool hit = (e_lo >= 110u && e_lo <= 132u);
  unsigned long long m = __ballot(hit);
  if (lane == 0) *flag = (__popcll(m) >= 32) ? 1 : 0;
}

// ---- convert input (bf16 or fp32) to fp32 workspace ---------------------
__global__ void convert_k(const void* __restrict__ in, float* __restrict__ out,
                          int n, const int* __restrict__ flag){
  bool isbf = (*flag != 0);
  int i = blockIdx.x * blockDim.x + threadIdx.x;
  int stride = gridDim.x * blockDim.x;
  if (isbf){
    const uint16_t* p = (const uint16_t*)in;
    for (; i < n; i += stride) out[i] = bf2f(p[i]);
  } else {
    const float* p = (const float*)in;
    for (; i < n; i += stride) out[i] = p[i];
  }
}

// ---- transpose W [128,512] -> WT [512,128] ------------------------------
__global__ void transpose_k(const float* __restrict__ a, const float* __restrict__ b,
                            float* __restrict__ at, float* __restrict__ bt){
  const float* in = blockIdx.x ? b : a;
  float* out = blockIdx.x ? bt : at;
  for (int o = threadIdx.x; o < D_ * W_; o += blockDim.x){
    int d = o >> 7, w = o & (W_ - 1);
    out[o] = in[w * D_ + d];
  }
}

union F4 { float4 v; float f[4]; };

// ---- projection: outA = x @ W^T (raw), lin = proj . wout ----------------
__global__ __launch_bounds__(256) void proj_k(const float* __restrict__ x,
        const float* __restrict__ WT, const float* __restrict__ wout,
        float* __restrict__ outA, float* __restrict__ lin){
  __shared__ float xl[64 * 36];
  __shared__ float wl[64 * 128];
  int tid = threadIdx.x;
  int tx = tid & 31, ty = tid >> 5;
  int rowBase = blockIdx.x * 32;
  float acc[4][4] = {};
  for (int c = 0; c < 8; ++c){
    int d0 = c * 64;
    const float4* wt4 = (const float4*)(WT + (size_t)d0 * W_);
    float4* wl4 = (float4*)wl;
    #pragma unroll
    for (int p = 0; p < 8; ++p){ int q = tid + 256 * p; wl4[q] = wt4[q]; }
    #pragma unroll
    for (int p = 0; p < 2; ++p){
      int q = tid + 256 * p;
      int r = q >> 4, dq = q & 15;
      F4 v; v.v = *(const float4*)(x + (size_t)(rowBase + r) * D_ + d0 + dq * 4);
      xl[(dq*4+0)*36 + r] = v.f[0];
      xl[(dq*4+1)*36 + r] = v.f[1];
      xl[(dq*4+2)*36 + r] = v.f[2];
      xl[(dq*4+3)*36 + r] = v.f[3];
    }
    __syncthreads();
    #pragma unroll 4
    for (int d = 0; d < 64; ++d){
      F4 a, w;
      a.v = *(const float4*)(xl + d * 36 + ty * 4);
      w.v = *(const float4*)(wl + d * 128 + tx * 4);
      #pragma unroll
      for (int i = 0; i < 4; ++i)
        #pragma unroll
        for (int j = 0; j < 4; ++j)
          acc[i][j] = fmaf(a.f[i], w.f[j], acc[i][j]);
    }
    __syncthreads();
  }
  F4 wo; wo.v = *(const float4*)(wout + tx * 4);
  #pragma unroll
  for (int i = 0; i < 4; ++i){
    int r = rowBase + ty * 4 + i;
    float s = acc[i][0]*wo.f[0] + acc[i][1]*wo.f[1] + acc[i][2]*wo.f[2] + acc[i][3]*wo.f[3];
    #pragma unroll
    for (int off = 16; off >= 1; off >>= 1) s += __shfl_xor(s, off, 32);
    if (tx == 0) lin[r] = s;
    float4 o = make_float4(acc[i][0], acc[i][1], acc[i][2], acc[i][3]);
    *(float4*)(outA + (size_t)r * W_ + tx * 4) = o;
  }
}

// ---- scalar const: cbias = bias + a0 * sum(w_int); also zero fix counter
__global__ void cbias_k(const float* __restrict__ wint, const float* __restrict__ bias,
                        float* __restrict__ cbias, int* __restrict__ cnt){
  if (threadIdx.x == 0){
    float s = 0.f;
    for (int i = 0; i < W_; ++i) s += wint[i];
    cbias[0] = bias[0] + A0C * s;
    cnt[0] = 0;
  }
}

// ---- feature generation: K layout = [g*128 + w], g=0..4 -----------------
__global__ void featA_k(const float* __restrict__ ps, const float* __restrict__ wint,
                        uint16_t* __restrict__ fa){
  int idx = blockIdx.x * 256 + threadIdx.x;     // B*S*128 threads
  int row = idx >> 7, w = idx & 127;
  float p = ps[idx];
  float wi = wint[w];
  float p2 = p*p, p4 = p2*p2, p6 = p4*p2, p8 = p4*p4;
  uint16_t* o = fa + (size_t)row * 640 + w;
  o[0]   = f2bf(0.5f * wi * p);
  o[128] = f2bf(A1C * wi * p2);
  o[256] = f2bf(A2C * wi * p4);
  o[384] = f2bf(A3C * wi * p6);
  o[512] = f2bf(A4C * wi * p8);
}
__global__ void featB_k(const float* __restrict__ pt, uint16_t* __restrict__ fb){
  int idx = blockIdx.x * 256 + threadIdx.x;
  int row = idx >> 7, w = idx & 127;
  float q = pt[idx];
  float q2 = q*q, q4 = q2*q2, q6 = q4*q2, q8 = q4*q4;
  uint16_t* o = fb + (size_t)row * 640 + w;
  o[0]   = f2bf(q);
  o[128] = f2bf(q2);
  o[256] = f2bf(q4);
  o[384] = f2bf(q6);
  o[512] = f2bf(q8);
}

// ---- per-(b,w) max |pt| -------------------------------------------------
__global__ void maxT_k(const float* __restrict__ pt, float* __restrict__ maxT){
  int w = blockIdx.x & 127, b = blockIdx.x >> 7;
  int tid = threadIdx.x;
  float m = 0.f;
  for (int t = tid; t < T_; t += 256)
    m = fmaxf(m, fabsf(pt[((size_t)b * T_ + t) * W_ + w]));
  #pragma unroll
  for (int off = 32; off >= 1; off >>= 1) m = fmaxf(m, __shfl_xor(m, off, 64));
  __shared__ float red[4];
  if ((tid & 63) == 0) red[tid >> 6] = m;
  __syncthreads();
  if (tid == 0)
    maxT[b * W_ + w] = fmaxf(fmaxf(red[0], red[1]), fmaxf(red[2], red[3]));
}

// ---- main GEMM: 128x128 tile, 4 waves, 16x16x32 bf16 MFMA, K=640 --------
__global__ __launch_bounds__(256) void gemm_k(const uint16_t* __restrict__ fA,
      const uint16_t* __restrict__ fB, const float* __restrict__ slin,
      const float* __restrict__ tlin, const float* __restrict__ cbias,
      const int* __restrict__ flag, void* __restrict__ outv){
  __shared__ __align__(16) uint16_t As[128 * 32];
  __shared__ __align__(16) uint16_t Bs[128 * 32];
  int tid = threadIdx.x, lane = tid & 63, wv = tid >> 6;
  int quad = lane >> 4, lr = lane & 15;
  int rowT = blockIdx.y * 128, colT = blockIdx.x * 128;
  int b = rowT >> 12;
  int r0 = lane >> 2, c0 = (lane & 3) * 8;
  int mBase = (wv & 1) * 64, nBase = (wv >> 1) * 64;

  f32x4 acc[4][4];
  #pragma unroll
  for (int i = 0; i < 4; ++i)
    #pragma unroll
    for (int j = 0; j < 4; ++j)
      acc[i][j] = (f32x4){0.f, 0.f, 0.f, 0.f};

  const uint16_t* aBase = fA + (size_t)rowT * 640;
  const uint16_t* bBase = fB + ((size_t)b * T_ + colT) * 640;

  for (int step = 0; step < 20; ++step){
    int kc = step * 32;
    #pragma unroll
    for (int h = 0; h < 2; ++h){
      int q = 2 * wv + h;
      gl_lds16(aBase + (size_t)(16 * q + r0) * 640 + kc + c0, &As[q * 512]);
      gl_lds16(bBase + (size_t)(16 * q + r0) * 640 + kc + c0, &Bs[q * 512]);
    }
    __syncthreads();
    bf16x8 af[4], bfr[4];
    #pragma unroll
    for (int i = 0; i < 4; ++i)
      af[i] = *(const bf16x8*)&As[(mBase + i * 16 + lr) * 32 + quad * 8];
    #pragma unroll
    for (int j = 0; j < 4; ++j)
      bfr[j] = *(const bf16x8*)&Bs[(nBase + j * 16 + lr) * 32 + quad * 8];
    #pragma unroll
    for (int i = 0; i < 4; ++i)
      #pragma unroll
      for (int j = 0; j < 4; ++j)
        acc[i][j] = __builtin_amdgcn_mfma_f32_16x16x32_bf16(af[i], bfr[j], acc[i][j], 0, 0, 0);
    __syncthreads();
  }

  float cb = cbias[0];
  bool isbf = (*flag != 0);
  #pragma unroll
  for (int i = 0; i < 4; ++i){
    #pragma unroll
    for (int r = 0; r < 4; ++r){
      int row = rowT + mBase + i * 16 + quad * 4 + r;
      float sl = slin[row] + cb;
      #pragma unroll
      for (int j = 0; j < 4; ++j){
        int t = colT + nBase + j * 16 + lr;
        float v = acc[i][j][r] + sl + tlin[b * T_ + t];
        size_t oi = (size_t)row * T_ + t;
        if (isbf) ((uint16_t*)outv)[oi] = f2bf(v);
        else      ((float*)outv)[oi] = v;
      }
    }
  }
}

// ---- sparse outlier scan: exact fix list for |z| > ZCUT -----------------
__global__ void flagscan_k(const float* __restrict__ ps, const float* __restrict__ pt,
        const float* __restrict__ wint, const float* __restrict__ maxT,
        const uint16_t* __restrict__ fA, const uint16_t* __restrict__ fB,
        uint32_t* __restrict__ listI, float* __restrict__ listV, int* __restrict__ cnt){
  __shared__ int nf;
  __shared__ uint16_t fs[S_];
  int w = blockIdx.x, b = blockIdx.y;
  int tid = threadIdx.x;
  float wi = wint[w], mt = maxT[b * W_ + w];
  if (tid == 0) nf = 0;
  __syncthreads();
  for (int s = tid; s < S_; s += 256){
    float p = ps[((size_t)b * S_ + s) * W_ + w];
    if (fabsf(p) * mt > ZCUT){ int k = atomicAdd(&nf, 1); fs[k] = (uint16_t)s; }
  }
  __syncthreads();
  int n = nf;
  for (int f = 0; f < n; ++f){
    int s = fs[f];
    float p = ps[((size_t)b * S_ + s) * W_ + w];
    const uint16_t* fa = fA + ((size_t)b * S_ + s) * 640 + w;
    float a0 = bf2f(fa[0]),   a1 = bf2f(fa[128]), a2 = bf2f(fa[256]);
    float a3 = bf2f(fa[384]), a4 = bf2f(fa[512]);
    for (int t = tid; t < T_; t += 256){
      float q = pt[((size_t)b * T_ + t) * W_ + w];
      float z = p * q;
      if (fabsf(z) > ZCUT){
        const uint16_t* fb = fB + ((size_t)b * T_ + t) * 640 + w;
        float dot = a0 * bf2f(fb[0]) + a1 * bf2f(fb[128]) + a2 * bf2f(fb[256])
                  + a3 * bf2f(fb[384]) + a4 * bf2f(fb[512]);
        float sil = z / (1.0f + __expf(-z));
        float corr = wi * sil - dot - A0C * wi;
        int j = atomicAdd(cnt, 1);
        if (j < FIXCAP){
          listI[j] = (uint32_t)(((size_t)b * S_ + s) * T_ + t);
          listV[j] = corr;
        }
      }
    }
  }
}

// ---- apply corrections (CAS on 32-bit words for bf16 halves) ------------
__global__ void apply_k(const uint32_t* __restrict__ listI, const float* __restrict__ listV,
                        const int* __restrict__ cnt, const int* __restrict__ flag,
                        void* __restrict__ outv){
  int n = *cnt; if (n > FIXCAP) n = FIXCAP;
  bool isbf = (*flag != 0);
  int i = blockIdx.x * blockDim.x + threadIdx.x;
  int stride = gridDim.x * blockDim.x;
  for (; i < n; i += stride){
    uint32_t idx = listI[i];
    float v = listV[i];
    if (isbf){
      uint32_t* wp = (uint32_t*)outv + (idx >> 1);
      bool hi = (idx & 1u) != 0;
      uint32_t assumed, old = *wp;
      do {
        assumed = old;
        uint16_t h = hi ? (uint16_t)(assumed >> 16) : (uint16_t)(assumed & 0xFFFFu);
        uint16_t nh = f2bf(bf2f(h) + v);
        uint32_t nw = hi ? ((assumed & 0x0000FFFFu) | ((uint32_t)nh << 16))
                         : ((assumed & 0xFFFF0000u) | (uint32_t)nh);
        old = atomicCAS(wp, assumed, nw);
      } while (old != assumed);
    } else {
      atomicAdd((float*)outv + idx, v);
    }
  }
}

extern "C" void kernel_launch(void* const* d_in, const int* in_sizes, int n_in,
                              void* d_out, int out_size, void* d_ws, size_t ws_size,
                              hipStream_t stream){
  char* ws = (char*)d_ws;
  size_t off = 0;
  auto alloc = [&](size_t bytes)->char*{
    char* p = ws + off; off += (bytes + 255) & ~(size_t)255; return p;
  };
  int*      flag = (int*)     alloc(4);
  float*    srcf = (float*)   alloc((size_t)B_*S_*D_*4);
  float*    tgtf = (float*)   alloc((size_t)B_*T_*D_*4);
  float*    Wsf  = (float*)   alloc((size_t)W_*D_*4);
  float*    Wtf  = (float*)   alloc((size_t)W_*D_*4);
  float*    wsof = (float*)   alloc(W_*4);
  float*    wtof = (float*)   alloc(W_*4);
  float*    wif  = (float*)   alloc(W_*4);
  float*    bf   = (float*)   alloc(4);
  float*    WsT  = (float*)   alloc((size_t)D_*W_*4);
  float*    WtT  = (float*)   alloc((size_t)D_*W_*4);
  float*    ps   = (float*)   alloc((size_t)B_*S_*W_*4);
  float*    pt   = (float*)   alloc((size_t)B_*T_*W_*4);
  float*    slin = (float*)   alloc((size_t)B_*S_*4);
  float*    tlin = (float*)   alloc((size_t)B_*T_*4);
  float*    maxT = (float*)   alloc((size_t)B_*W_*4);
  float*    cbias= (float*)   alloc(4);
  int*      cnt  = (int*)     alloc(4);
  uint16_t* featA= (uint16_t*)alloc((size_t)B_*S_*640*2);
  uint16_t* featB= (uint16_t*)alloc((size_t)B_*T_*640*2);
  uint32_t* listI= (uint32_t*)alloc((size_t)FIXCAP*4);
  float*    listV= (float*)   alloc((size_t)FIXCAP*4);

  hipLaunchKernelGGL(detect_k, dim3(1), dim3(64), 0, stream,
                     (const uint32_t*)d_in[0], flag);
  const int nbig = B_*S_*D_;
  hipLaunchKernelGGL(convert_k, dim3(2048), dim3(256), 0, stream, d_in[0], srcf, nbig, flag);
  hipLaunchKernelGGL(convert_k, dim3(2048), dim3(256), 0, stream, d_in[1], tgtf, nbig, flag);
  hipLaunchKernelGGL(convert_k, dim3(256),  dim3(256), 0, stream, d_in[2], Wsf, W_*D_, flag);
  hipLaunchKernelGGL(convert_k, dim3(256),  dim3(256), 0, stream, d_in[3], Wtf, W_*D_, flag);
  hipLaunchKernelGGL(convert_k, dim3(1),    dim3(256), 0, stream, d_in[4], wsof, W_, flag);
  hipLaunchKernelGGL(convert_k, dim3(1),    dim3(256), 0, stream, d_in[5], wtof, W_, flag);
  hipLaunchKernelGGL(convert_k, dim3(1),    dim3(256), 0, stream, d_in[6], wif, W_, flag);
  hipLaunchKernelGGL(convert_k, dim3(1),    dim3(256), 0, stream, d_in[7], bf, 1, flag);
  hipLaunchKernelGGL(transpose_k, dim3(2), dim3(256), 0, stream, Wsf, Wtf, WsT, WtT);
  hipLaunchKernelGGL(proj_k, dim3(B_*S_/32), dim3(256), 0, stream, srcf, WsT, wsof, ps, slin);
  hipLaunchKernelGGL(proj_k, dim3(B_*T_/32), dim3(256), 0, stream, tgtf, WtT, wtof, pt, tlin);
  hipLaunchKernelGGL(cbias_k, dim3(1), dim3(64), 0, stream, wif, bf, cbias, cnt);
  hipLaunchKernelGGL(maxT_k, dim3(B_*W_), dim3(256), 0, stream, pt, maxT);
  hipLaunchKernelGGL(featA_k, dim3(B_*S_*W_/256), dim3(256), 0, stream, ps, wif, featA);
  hipLaunchKernelGGL(featB_k, dim3(B_*T_*W_/256), dim3(256), 0, stream, pt, featB);
  hipLaunchKernelGGL(gemm_k, dim3(T_/128, B_*S_/128), dim3(256), 0, stream,
                     featA, featB, slin, tlin, cbias, flag, d_out);
  hipLaunchKernelGGL(flagscan_k, dim3(W_, B_), dim3(256), 0, stream,
                     ps, pt, wif, maxT, featA, featB, listI, listV, cnt);
  hipLaunchKernelGGL(apply_k, dim3(256), dim3(256), 0, stream,
                     listI, listV, cnt, flag, d_out);
}

// Round 3
// 633.692 us; speedup vs baseline: 1.7434x; 1.2028x over previous
//
#include <hip/hip_runtime.h>
#include <cstdint>
#include <cstddef>

#define B_ 2
#define S_ 4096
#define T_ 4096
#define D_ 512
#define W_ 128

// degree-4 poly in t=z^2 for h(t) = silu(z) - z/2, fit on t in [0, 6.25]
#define A0C (-0.0006958f)
#define A1C (0.2529946f)
#define A2C (-0.0226345f)
#define A3C (0.0022173f)
#define A4C (-0.00011668f)
#define ZCUT 2.5f
#define FIXCAP (1024*1024)

typedef __attribute__((ext_vector_type(8))) short bf16x8;
typedef __attribute__((ext_vector_type(4))) float f32x4;

__device__ __forceinline__ uint16_t f2bf(float f){
  uint32_t u = __float_as_uint(f);
  u += 0x7FFFu + ((u >> 16) & 1u);        // round-to-nearest-even
  return (uint16_t)(u >> 16);
}
__device__ __forceinline__ float bf2f(uint16_t h){
  return __uint_as_float(((uint32_t)h) << 16);
}

__device__ __forceinline__ void gl_lds16(const void* g, void* l){
  __builtin_amdgcn_global_load_lds(
      (const __attribute__((address_space(1))) void*)g,
      (__attribute__((address_space(3))) void*)l, 16, 0, 0);
}

// ---- dtype detector: bf16 low-half has an exponent field, fp32 has mantissa bits
__global__ void detect_k(const uint32_t* __restrict__ src, int* __restrict__ flag){
  int lane = threadIdx.x;
  uint32_t u = src[lane];
  uint32_t e_lo = (u >> 7) & 0xFFu;
  bool hit = (e_lo >= 110u && e_lo <= 132u);
  unsigned long long m = __ballot(hit);
  if (lane == 0) *flag = (__popcll(m) >= 32) ? 1 : 0;
}

// ---- convert input (bf16 or fp32) to fp32 workspace ---------------------
__global__ void convert_k(const void* __restrict__ in, float* __restrict__ out,
                          int n, const int* __restrict__ flag){
  bool isbf = (*flag != 0);
  int i = blockIdx.x * blockDim.x + threadIdx.x;
  int stride = gridDim.x * blockDim.x;
  if (isbf){
    const uint16_t* p = (const uint16_t*)in;
    for (; i < n; i += stride) out[i] = bf2f(p[i]);
  } else {
    const float* p = (const float*)in;
    for (; i < n; i += stride) out[i] = p[i];
  }
}

// ---- transpose W [128,512] -> WT [512,128] ------------------------------
__global__ void transpose_k(const float* __restrict__ a, const float* __restrict__ b,
                            float* __restrict__ at, float* __restrict__ bt){
  const float* in = blockIdx.x ? b : a;
  float* out = blockIdx.x ? bt : at;
  for (int o = threadIdx.x; o < D_ * W_; o += blockDim.x){
    int d = o >> 7, w = o & (W_ - 1);
    out[o] = in[w * D_ + d];
  }
}

union F4 { float4 v; float f[4]; };

// ---- projection: outA = x @ W^T (raw), lin = proj . wout ----------------
__global__ __launch_bounds__(256) void proj_k(const float* __restrict__ x,
        const float* __restrict__ WT, const float* __restrict__ wout,
        float* __restrict__ outA, float* __restrict__ lin){
  __shared__ float xl[64 * 36];
  __shared__ float wl[64 * 128];
  int tid = threadIdx.x;
  int tx = tid & 31, ty = tid >> 5;
  int rowBase = blockIdx.x * 32;
  float acc[4][4] = {};
  for (int c = 0; c < 8; ++c){
    int d0 = c * 64;
    const float4* wt4 = (const float4*)(WT + (size_t)d0 * W_);
    float4* wl4 = (float4*)wl;
    #pragma unroll
    for (int p = 0; p < 8; ++p){ int q = tid + 256 * p; wl4[q] = wt4[q]; }
    #pragma unroll
    for (int p = 0; p < 2; ++p){
      int q = tid + 256 * p;
      int r = q >> 4, dq = q & 15;
      F4 v; v.v = *(const float4*)(x + (size_t)(rowBase + r) * D_ + d0 + dq * 4);
      xl[(dq*4+0)*36 + r] = v.f[0];
      xl[(dq*4+1)*36 + r] = v.f[1];
      xl[(dq*4+2)*36 + r] = v.f[2];
      xl[(dq*4+3)*36 + r] = v.f[3];
    }
    __syncthreads();
    #pragma unroll 4
    for (int d = 0; d < 64; ++d){
      F4 a, w;
      a.v = *(const float4*)(xl + d * 36 + ty * 4);
      w.v = *(const float4*)(wl + d * 128 + tx * 4);
      #pragma unroll
      for (int i = 0; i < 4; ++i)
        #pragma unroll
        for (int j = 0; j < 4; ++j)
          acc[i][j] = fmaf(a.f[i], w.f[j], acc[i][j]);
    }
    __syncthreads();
  }
  F4 wo; wo.v = *(const float4*)(wout + tx * 4);
  #pragma unroll
  for (int i = 0; i < 4; ++i){
    int r = rowBase + ty * 4 + i;
    float s = acc[i][0]*wo.f[0] + acc[i][1]*wo.f[1] + acc[i][2]*wo.f[2] + acc[i][3]*wo.f[3];
    #pragma unroll
    for (int off = 16; off >= 1; off >>= 1) s += __shfl_xor(s, off, 32);
    if (tx == 0) lin[r] = s;
    float4 o = make_float4(acc[i][0], acc[i][1], acc[i][2], acc[i][3]);
    *(float4*)(outA + (size_t)r * W_ + tx * 4) = o;
  }
}

// ---- LDS-tiled transpose [B*rows,128] -> [B][128][rows] -----------------
__global__ __launch_bounds__(256) void transposeP_k(const float* __restrict__ ps,
        const float* __restrict__ pt, float* __restrict__ psT, float* __restrict__ ptT){
  __shared__ float tile[64][65];
  const float* in = blockIdx.z ? pt : ps;
  float* out = blockIdx.z ? ptT : psT;
  int w0 = blockIdx.x * 64;
  int r0 = blockIdx.y * 64;
  int tid = threadIdx.x;
  #pragma unroll
  for (int it = 0; it < 4; ++it){
    int r = it * 16 + (tid >> 4);
    int wq = tid & 15;
    F4 v; v.v = *(const float4*)(in + (size_t)(r0 + r) * W_ + w0 + wq * 4);
    tile[wq*4+0][r] = v.f[0];
    tile[wq*4+1][r] = v.f[1];
    tile[wq*4+2][r] = v.f[2];
    tile[wq*4+3][r] = v.f[3];
  }
  __syncthreads();
  int b = r0 >> 12, s0 = r0 & (S_ - 1);
  #pragma unroll
  for (int it = 0; it < 4; ++it){
    int w = it * 16 + (tid >> 4);
    int sq = tid & 15;
    float4 o = make_float4(tile[w][sq*4+0], tile[w][sq*4+1],
                           tile[w][sq*4+2], tile[w][sq*4+3]);
    *(float4*)(out + ((size_t)(b * W_ + w0 + w)) * S_ + s0 + sq * 4) = o;
  }
}

// ---- scalar const: cbias = bias + a0 * sum(w_int); also zero fix counter
__global__ void cbias_k(const float* __restrict__ wint, const float* __restrict__ bias,
                        float* __restrict__ cbias, int* __restrict__ cnt){
  if (threadIdx.x == 0){
    float s = 0.f;
    for (int i = 0; i < W_; ++i) s += wint[i];
    cbias[0] = bias[0] + A0C * s;
    cnt[0] = 0;
  }
}

// ---- feature generation: K layout = [g*128 + w], g=0..4 -----------------
__global__ void featA_k(const float* __restrict__ ps, const float* __restrict__ wint,
                        uint16_t* __restrict__ fa){
  int idx = blockIdx.x * 256 + threadIdx.x;
  int row = idx >> 7, w = idx & 127;
  float p = ps[idx];
  float wi = wint[w];
  float p2 = p*p, p4 = p2*p2, p6 = p4*p2, p8 = p4*p4;
  uint16_t* o = fa + (size_t)row * 640 + w;
  o[0]   = f2bf(0.5f * wi * p);
  o[128] = f2bf(A1C * wi * p2);
  o[256] = f2bf(A2C * wi * p4);
  o[384] = f2bf(A3C * wi * p6);
  o[512] = f2bf(A4C * wi * p8);
}
__global__ void featB_k(const float* __restrict__ pt, uint16_t* __restrict__ fb){
  int idx = blockIdx.x * 256 + threadIdx.x;
  int row = idx >> 7, w = idx & 127;
  float q = pt[idx];
  float q2 = q*q, q4 = q2*q2, q6 = q4*q2, q8 = q4*q4;
  uint16_t* o = fb + (size_t)row * 640 + w;
  o[0]   = f2bf(q);
  o[128] = f2bf(q2);
  o[256] = f2bf(q4);
  o[384] = f2bf(q6);
  o[512] = f2bf(q8);
}

// ---- per-(b,w) max |pt| from transposed layout (coalesced) --------------
__global__ void maxT_k(const float* __restrict__ ptT, float* __restrict__ maxT){
  int bw = blockIdx.x;
  int tid = threadIdx.x;
  const float* c = ptT + (size_t)bw * T_;
  float m = 0.f;
  for (int t = tid; t < T_; t += 256) m = fmaxf(m, fabsf(c[t]));
  #pragma unroll
  for (int off = 32; off >= 1; off >>= 1) m = fmaxf(m, __shfl_xor(m, off, 64));
  __shared__ float red[4];
  if ((tid & 63) == 0) red[tid >> 6] = m;
  __syncthreads();
  if (tid == 0)
    maxT[bw] = fmaxf(fmaxf(red[0], red[1]), fmaxf(red[2], red[3]));
}

// ---- main GEMM: 128x128 tile, 4 waves, 16x16x32 bf16 MFMA, K=640 --------
__global__ __launch_bounds__(256) void gemm_k(const uint16_t* __restrict__ fA,
      const uint16_t* __restrict__ fB, const float* __restrict__ slin,
      const float* __restrict__ tlin, const float* __restrict__ cbias,
      const int* __restrict__ flag, void* __restrict__ outv){
  __shared__ __align__(16) uint16_t As[128 * 32];
  __shared__ __align__(16) uint16_t Bs[128 * 32];
  int tid = threadIdx.x, lane = tid & 63, wv = tid >> 6;
  int quad = lane >> 4, lr = lane & 15;
  int rowT = blockIdx.y * 128, colT = blockIdx.x * 128;
  int b = rowT >> 12;
  int r0 = lane >> 2, c0 = (lane & 3) * 8;
  int mBase = (wv & 1) * 64, nBase = (wv >> 1) * 64;

  f32x4 acc[4][4];
  #pragma unroll
  for (int i = 0; i < 4; ++i)
    #pragma unroll
    for (int j = 0; j < 4; ++j)
      acc[i][j] = (f32x4){0.f, 0.f, 0.f, 0.f};

  const uint16_t* aBase = fA + (size_t)rowT * 640;
  const uint16_t* bBase = fB + ((size_t)b * T_ + colT) * 640;

  for (int step = 0; step < 20; ++step){
    int kc = step * 32;
    #pragma unroll
    for (int h = 0; h < 2; ++h){
      int q = 2 * wv + h;
      gl_lds16(aBase + (size_t)(16 * q + r0) * 640 + kc + c0, &As[q * 512]);
      gl_lds16(bBase + (size_t)(16 * q + r0) * 640 + kc + c0, &Bs[q * 512]);
    }
    __syncthreads();
    bf16x8 af[4], bfr[4];
    #pragma unroll
    for (int i = 0; i < 4; ++i)
      af[i] = *(const bf16x8*)&As[(mBase + i * 16 + lr) * 32 + quad * 8];
    #pragma unroll
    for (int j = 0; j < 4; ++j)
      bfr[j] = *(const bf16x8*)&Bs[(nBase + j * 16 + lr) * 32 + quad * 8];
    #pragma unroll
    for (int i = 0; i < 4; ++i)
      #pragma unroll
      for (int j = 0; j < 4; ++j)
        acc[i][j] = __builtin_amdgcn_mfma_f32_16x16x32_bf16(af[i], bfr[j], acc[i][j], 0, 0, 0);
    __syncthreads();
  }

  float cb = cbias[0];
  bool isbf = (*flag != 0);
  #pragma unroll
  for (int i = 0; i < 4; ++i){
    #pragma unroll
    for (int r = 0; r < 4; ++r){
      int row = rowT + mBase + i * 16 + quad * 4 + r;
      float sl = slin[row] + cb;
      #pragma unroll
      for (int j = 0; j < 4; ++j){
        int t = colT + nBase + j * 16 + lr;
        float v = acc[i][j][r] + sl + tlin[b * T_ + t];
        size_t oi = (size_t)row * T_ + t;
        if (isbf) ((uint16_t*)outv)[oi] = f2bf(v);
        else      ((float*)outv)[oi] = v;
      }
    }
  }
}

// ---- sparse outlier scan (coalesced via psT/ptT): fix |z| > ZCUT --------
__global__ void flagscan_k(const float* __restrict__ psT, const float* __restrict__ ptT,
        const float* __restrict__ wint, const float* __restrict__ maxT,
        const uint16_t* __restrict__ fA, const uint16_t* __restrict__ fB,
        uint32_t* __restrict__ listI, float* __restrict__ listV, int* __restrict__ cnt){
  __shared__ int nf;
  __shared__ uint16_t fs[S_];
  int w = blockIdx.x, b = blockIdx.y;
  int tid = threadIdx.x;
  float wi = wint[w], mt = maxT[b * W_ + w];
  const float* psc = psT + (size_t)(b * W_ + w) * S_;
  const float* ptc = ptT + (size_t)(b * W_ + w) * T_;
  if (tid == 0) nf = 0;
  __syncthreads();
  for (int s = tid; s < S_; s += 256){
    float p = psc[s];
    if (fabsf(p) * mt > ZCUT){ int k = atomicAdd(&nf, 1); fs[k] = (uint16_t)s; }
  }
  __syncthreads();
  int n = nf;
  for (int f = 0; f < n; ++f){
    int s = fs[f];
    float p = psc[s];
    const uint16_t* fa = fA + ((size_t)b * S_ + s) * 640 + w;
    float a0 = bf2f(fa[0]),   a1 = bf2f(fa[128]), a2 = bf2f(fa[256]);
    float a3 = bf2f(fa[384]), a4 = bf2f(fa[512]);
    for (int t = tid; t < T_; t += 256){
      float q = ptc[t];
      float z = p * q;
      if (fabsf(z) > ZCUT){
        const uint16_t* fb = fB + ((size_t)b * T_ + t) * 640 + w;
        float dot = a0 * bf2f(fb[0]) + a1 * bf2f(fb[128]) + a2 * bf2f(fb[256])
                  + a3 * bf2f(fb[384]) + a4 * bf2f(fb[512]);
        float sil = z / (1.0f + __expf(-z));
        float corr = wi * sil - dot - A0C * wi;
        int j = atomicAdd(cnt, 1);
        if (j < FIXCAP){
          listI[j] = (uint32_t)(((size_t)b * S_ + s) * T_ + t);
          listV[j] = corr;
        }
      }
    }
  }
}

// ---- apply corrections (CAS on 32-bit words for bf16 halves) ------------
__global__ void apply_k(const uint32_t* __restrict__ listI, const float* __restrict__ listV,
                        const int* __restrict__ cnt, const int* __restrict__ flag,
                        void* __restrict__ outv){
  int n = *cnt; if (n > FIXCAP) n = FIXCAP;
  bool isbf = (*flag != 0);
  int i = blockIdx.x * blockDim.x + threadIdx.x;
  int stride = gridDim.x * blockDim.x;
  for (; i < n; i += stride){
    uint32_t idx = listI[i];
    float v = listV[i];
    if (isbf){
      uint32_t* wp = (uint32_t*)outv + (idx >> 1);
      bool hi = (idx & 1u) != 0;
      uint32_t assumed, old = *wp;
      do {
        assumed = old;
        uint16_t h = hi ? (uint16_t)(assumed >> 16) : (uint16_t)(assumed & 0xFFFFu);
        uint16_t nh = f2bf(bf2f(h) + v);
        uint32_t nw = hi ? ((assumed & 0x0000FFFFu) | ((uint32_t)nh << 16))
                         : ((assumed & 0xFFFF0000u) | (uint32_t)nh);
        old = atomicCAS(wp, assumed, nw);
      } while (old != assumed);
    } else {
      atomicAdd((float*)outv + idx, v);
    }
  }
}

extern "C" void kernel_launch(void* const* d_in, const int* in_sizes, int n_in,
                              void* d_out, int out_size, void* d_ws, size_t ws_size,
                              hipStream_t stream){
  char* ws = (char*)d_ws;
  size_t off = 0;
  auto alloc = [&](size_t bytes)->char*{
    char* p = ws + off; off += (bytes + 255) & ~(size_t)255; return p;
  };
  int*      flag = (int*)     alloc(4);
  float*    srcf = (float*)   alloc((size_t)B_*S_*D_*4);
  float*    tgtf = (float*)   alloc((size_t)B_*T_*D_*4);
  float*    Wsf  = (float*)   alloc((size_t)W_*D_*4);
  float*    Wtf  = (float*)   alloc((size_t)W_*D_*4);
  float*    wsof = (float*)   alloc(W_*4);
  float*    wtof = (float*)   alloc(W_*4);
  float*    wif  = (float*)   alloc(W_*4);
  float*    bf   = (float*)   alloc(4);
  float*    WsT  = (float*)   alloc((size_t)D_*W_*4);
  float*    WtT  = (float*)   alloc((size_t)D_*W_*4);
  float*    ps   = (float*)   alloc((size_t)B_*S_*W_*4);
  float*    pt   = (float*)   alloc((size_t)B_*T_*W_*4);
  float*    psT  = (float*)   alloc((size_t)B_*S_*W_*4);
  float*    ptT  = (float*)   alloc((size_t)B_*T_*W_*4);
  float*    slin = (float*)   alloc((size_t)B_*S_*4);
  float*    tlin = (float*)   alloc((size_t)B_*T_*4);
  float*    maxT = (float*)   alloc((size_t)B_*W_*4);
  float*    cbias= (float*)   alloc(4);
  int*      cnt  = (int*)     alloc(4);
  uint16_t* featA= (uint16_t*)alloc((size_t)B_*S_*640*2);
  uint16_t* featB= (uint16_t*)alloc((size_t)B_*T_*640*2);
  uint32_t* listI= (uint32_t*)alloc((size_t)FIXCAP*4);
  float*    listV= (float*)   alloc((size_t)FIXCAP*4);

  hipLaunchKernelGGL(detect_k, dim3(1), dim3(64), 0, stream,
                     (const uint32_t*)d_in[0], flag);
  const int nbig = B_*S_*D_;
  hipLaunchKernelGGL(convert_k, dim3(2048), dim3(256), 0, stream, d_in[0], srcf, nbig, flag);
  hipLaunchKernelGGL(convert_k, dim3(2048), dim3(256), 0, stream, d_in[1], tgtf, nbig, flag);
  hipLaunchKernelGGL(convert_k, dim3(256),  dim3(256), 0, stream, d_in[2], Wsf, W_*D_, flag);
  hipLaunchKernelGGL(convert_k, dim3(256),  dim3(256), 0, stream, d_in[3], Wtf, W_*D_, flag);
  hipLaunchKernelGGL(convert_k, dim3(1),    dim3(256), 0, stream, d_in[4], wsof, W_, flag);
  hipLaunchKernelGGL(convert_k, dim3(1),    dim3(256), 0, stream, d_in[5], wtof, W_, flag);
  hipLaunchKernelGGL(convert_k, dim3(1),    dim3(256), 0, stream, d_in[6], wif, W_, flag);
  hipLaunchKernelGGL(convert_k, dim3(1),    dim3(256), 0, stream, d_in[7], bf, 1, flag);
  hipLaunchKernelGGL(transpose_k, dim3(2), dim3(256), 0, stream, Wsf, Wtf, WsT, WtT);
  hipLaunchKernelGGL(proj_k, dim3(B_*S_/32), dim3(256), 0, stream, srcf, WsT, wsof, ps, slin);
  hipLaunchKernelGGL(proj_k, dim3(B_*T_/32), dim3(256), 0, stream, tgtf, WtT, wtof, pt, tlin);
  hipLaunchKernelGGL(transposeP_k, dim3(2, B_*S_/64, 2), dim3(256), 0, stream,
                     ps, pt, psT, ptT);
  hipLaunchKernelGGL(cbias_k, dim3(1), dim3(64), 0, stream, wif, bf, cbias, cnt);
  hipLaunchKernelGGL(maxT_k, dim3(B_*W_), dim3(256), 0, stream, ptT, maxT);
  hipLaunchKernelGGL(featA_k, dim3(B_*S_*W_/256), dim3(256), 0, stream, ps, wif, featA);
  hipLaunchKernelGGL(featB_k, dim3(B_*T_*W_/256), dim3(256), 0, stream, pt, featB);
  hipLaunchKernelGGL(gemm_k, dim3(T_/128, B_*S_/128), dim3(256), 0, stream,
                     featA, featB, slin, tlin, cbias, flag, d_out);
  hipLaunchKernelGGL(flagscan_k, dim3(W_, B_), dim3(256), 0, stream,
                     psT, ptT, wif, maxT, featA, featB, listI, listV, cnt);
  hipLaunchKernelGGL(apply_k, dim3(256), dim3(256), 0, stream,
                     listI, listV, cnt, flag, d_out);
}

// Round 4
// 392.586 us; speedup vs baseline: 2.8141x; 1.6141x over previous
//
#include <hip/hip_runtime.h>
#include <cstdint>
#include <cstddef>

#define B_ 2
#define S_ 4096
#define T_ 4096
#define D_ 512
#define W_ 128

// degree-4 poly in t=z^2 for h(t) = silu(z) - z/2, fit on t in [0, 6.25]
#define A0C (-0.0006958f)
#define A1C (0.2529946f)
#define A2C (-0.0226345f)
#define A3C (0.0022173f)
#define A4C (-0.00011668f)
#define ZCUT 2.5f
#define ROWCAP 65536

typedef __attribute__((ext_vector_type(8))) short bf16x8;
typedef __attribute__((ext_vector_type(4))) float f32x4;

__device__ __forceinline__ uint16_t f2bf(float f){
  uint32_t u = __float_as_uint(f);
  u += 0x7FFFu + ((u >> 16) & 1u);        // round-to-nearest-even
  return (uint16_t)(u >> 16);
}
__device__ __forceinline__ float bf2f(uint16_t h){
  return __uint_as_float(((uint32_t)h) << 16);
}

__device__ __forceinline__ void gl_lds16(const void* g, void* l){
  __builtin_amdgcn_global_load_lds(
      (const __attribute__((address_space(1))) void*)g,
      (__attribute__((address_space(3))) void*)l, 16, 0, 0);
}

// ---- dtype detector: bf16 low-half has an exponent field, fp32 has mantissa bits
__global__ void detect_k(const uint32_t* __restrict__ src, int* __restrict__ flag){
  int lane = threadIdx.x;
  uint32_t u = src[lane];
  uint32_t e_lo = (u >> 7) & 0xFFu;
  bool hit = (e_lo >= 110u && e_lo <= 132u);
  unsigned long long m = __ballot(hit);
  if (lane == 0) *flag = (__popcll(m) >= 32) ? 1 : 0;
}

// ---- convert input (bf16 or fp32) to fp32 workspace ---------------------
__global__ void convert_k(const void* __restrict__ in, float* __restrict__ out,
                          int n, const int* __restrict__ flag){
  bool isbf = (*flag != 0);
  int i = blockIdx.x * blockDim.x + threadIdx.x;
  int stride = gridDim.x * blockDim.x;
  if (isbf){
    const uint16_t* p = (const uint16_t*)in;
    for (; i < n; i += stride) out[i] = bf2f(p[i]);
  } else {
    const float* p = (const float*)in;
    for (; i < n; i += stride) out[i] = p[i];
  }
}

// ---- transpose W [128,512] -> WT [512,128] ------------------------------
__global__ void transpose_k(const float* __restrict__ a, const float* __restrict__ b,
                            float* __restrict__ at, float* __restrict__ bt){
  const float* in = blockIdx.x ? b : a;
  float* out = blockIdx.x ? bt : at;
  for (int o = threadIdx.x; o < D_ * W_; o += blockDim.x){
    int d = o >> 7, w = o & (W_ - 1);
    out[o] = in[w * D_ + d];
  }
}

union F4 { float4 v; float f[4]; };

// ---- projection: outA = x @ W^T (raw), lin = proj . wout ----------------
__global__ __launch_bounds__(256) void proj_k(const float* __restrict__ x,
        const float* __restrict__ WT, const float* __restrict__ wout,
        float* __restrict__ outA, float* __restrict__ lin){
  __shared__ float xl[64 * 36];
  __shared__ float wl[64 * 128];
  int tid = threadIdx.x;
  int tx = tid & 31, ty = tid >> 5;
  int rowBase = blockIdx.x * 32;
  float acc[4][4] = {};
  for (int c = 0; c < 8; ++c){
    int d0 = c * 64;
    const float4* wt4 = (const float4*)(WT + (size_t)d0 * W_);
    float4* wl4 = (float4*)wl;
    #pragma unroll
    for (int p = 0; p < 8; ++p){ int q = tid + 256 * p; wl4[q] = wt4[q]; }
    #pragma unroll
    for (int p = 0; p < 2; ++p){
      int q = tid + 256 * p;
      int r = q >> 4, dq = q & 15;
      F4 v; v.v = *(const float4*)(x + (size_t)(rowBase + r) * D_ + d0 + dq * 4);
      xl[(dq*4+0)*36 + r] = v.f[0];
      xl[(dq*4+1)*36 + r] = v.f[1];
      xl[(dq*4+2)*36 + r] = v.f[2];
      xl[(dq*4+3)*36 + r] = v.f[3];
    }
    __syncthreads();
    #pragma unroll 4
    for (int d = 0; d < 64; ++d){
      F4 a, w;
      a.v = *(const float4*)(xl + d * 36 + ty * 4);
      w.v = *(const float4*)(wl + d * 128 + tx * 4);
      #pragma unroll
      for (int i = 0; i < 4; ++i)
        #pragma unroll
        for (int j = 0; j < 4; ++j)
          acc[i][j] = fmaf(a.f[i], w.f[j], acc[i][j]);
    }
    __syncthreads();
  }
  F4 wo; wo.v = *(const float4*)(wout + tx * 4);
  #pragma unroll
  for (int i = 0; i < 4; ++i){
    int r = rowBase + ty * 4 + i;
    float s = acc[i][0]*wo.f[0] + acc[i][1]*wo.f[1] + acc[i][2]*wo.f[2] + acc[i][3]*wo.f[3];
    #pragma unroll
    for (int off = 16; off >= 1; off >>= 1) s += __shfl_xor(s, off, 32);
    if (tx == 0) lin[r] = s;
    float4 o = make_float4(acc[i][0], acc[i][1], acc[i][2], acc[i][3]);
    *(float4*)(outA + (size_t)r * W_ + tx * 4) = o;
  }
}

// ---- LDS-tiled transpose [B*rows,128] -> [B][128][rows] -----------------
__global__ __launch_bounds__(256) void transposeP_k(const float* __restrict__ ps,
        const float* __restrict__ pt, float* __restrict__ psT, float* __restrict__ ptT){
  __shared__ float tile[64][65];
  const float* in = blockIdx.z ? pt : ps;
  float* out = blockIdx.z ? ptT : psT;
  int w0 = blockIdx.x * 64;
  int r0 = blockIdx.y * 64;
  int tid = threadIdx.x;
  #pragma unroll
  for (int it = 0; it < 4; ++it){
    int r = it * 16 + (tid >> 4);
    int wq = tid & 15;
    F4 v; v.v = *(const float4*)(in + (size_t)(r0 + r) * W_ + w0 + wq * 4);
    tile[wq*4+0][r] = v.f[0];
    tile[wq*4+1][r] = v.f[1];
    tile[wq*4+2][r] = v.f[2];
    tile[wq*4+3][r] = v.f[3];
  }
  __syncthreads();
  int b = r0 >> 12, s0 = r0 & (S_ - 1);
  #pragma unroll
  for (int it = 0; it < 4; ++it){
    int w = it * 16 + (tid >> 4);
    int sq = tid & 15;
    float4 o = make_float4(tile[w][sq*4+0], tile[w][sq*4+1],
                           tile[w][sq*4+2], tile[w][sq*4+3]);
    *(float4*)(out + ((size_t)(b * W_ + w0 + w)) * S_ + s0 + sq * 4) = o;
  }
}

// ---- scalar const: cbias = bias + a0 * sum(w_int); zero row counter -----
__global__ void cbias_k(const float* __restrict__ wint, const float* __restrict__ bias,
                        float* __restrict__ cbias, int* __restrict__ rowCnt){
  if (threadIdx.x == 0){
    float s = 0.f;
    for (int i = 0; i < W_; ++i) s += wint[i];
    cbias[0] = bias[0] + A0C * s;
    rowCnt[0] = 0;
  }
}

// ---- feature generation: K layout = [g*128 + w], g=0..4 -----------------
__global__ void featA_k(const float* __restrict__ ps, const float* __restrict__ wint,
                        uint16_t* __restrict__ fa){
  int idx = blockIdx.x * 256 + threadIdx.x;
  int row = idx >> 7, w = idx & 127;
  float p = ps[idx];
  float wi = wint[w];
  float p2 = p*p, p4 = p2*p2, p6 = p4*p2, p8 = p4*p4;
  uint16_t* o = fa + (size_t)row * 640 + w;
  o[0]   = f2bf(0.5f * wi * p);
  o[128] = f2bf(A1C * wi * p2);
  o[256] = f2bf(A2C * wi * p4);
  o[384] = f2bf(A3C * wi * p6);
  o[512] = f2bf(A4C * wi * p8);
}
__global__ void featB_k(const float* __restrict__ pt, uint16_t* __restrict__ fb){
  int idx = blockIdx.x * 256 + threadIdx.x;
  int row = idx >> 7, w = idx & 127;
  float q = pt[idx];
  float q2 = q*q, q4 = q2*q2, q6 = q4*q2, q8 = q4*q4;
  uint16_t* o = fb + (size_t)row * 640 + w;
  o[0]   = f2bf(q);
  o[128] = f2bf(q2);
  o[256] = f2bf(q4);
  o[384] = f2bf(q6);
  o[512] = f2bf(q8);
}

// ---- per-(b,w) max |pt| from transposed layout (coalesced) --------------
__global__ void maxT_k(const float* __restrict__ ptT, float* __restrict__ maxT){
  int bw = blockIdx.x;
  int tid = threadIdx.x;
  const float* c = ptT + (size_t)bw * T_;
  float m = 0.f;
  for (int t = tid; t < T_; t += 256) m = fmaxf(m, fabsf(c[t]));
  #pragma unroll
  for (int off = 32; off >= 1; off >>= 1) m = fmaxf(m, __shfl_xor(m, off, 64));
  __shared__ float red[4];
  if ((tid & 63) == 0) red[tid >> 6] = m;
  __syncthreads();
  if (tid == 0)
    maxT[bw] = fmaxf(fmaxf(red[0], red[1]), fmaxf(red[2], red[3]));
}

// ---- main GEMM: 128x128 tile, 4 waves, 16x16x32 bf16 MFMA, K=640 --------
__global__ __launch_bounds__(256) void gemm_k(const uint16_t* __restrict__ fA,
      const uint16_t* __restrict__ fB, const float* __restrict__ slin,
      const float* __restrict__ tlin, const float* __restrict__ cbias,
      const int* __restrict__ flag, void* __restrict__ outv){
  __shared__ __align__(16) uint16_t As[128 * 32];
  __shared__ __align__(16) uint16_t Bs[128 * 32];
  int tid = threadIdx.x, lane = tid & 63, wv = tid >> 6;
  int quad = lane >> 4, lr = lane & 15;
  int rowT = blockIdx.y * 128, colT = blockIdx.x * 128;
  int b = rowT >> 12;
  int r0 = lane >> 2, c0 = (lane & 3) * 8;
  int mBase = (wv & 1) * 64, nBase = (wv >> 1) * 64;

  f32x4 acc[4][4];
  #pragma unroll
  for (int i = 0; i < 4; ++i)
    #pragma unroll
    for (int j = 0; j < 4; ++j)
      acc[i][j] = (f32x4){0.f, 0.f, 0.f, 0.f};

  const uint16_t* aBase = fA + (size_t)rowT * 640;
  const uint16_t* bBase = fB + ((size_t)b * T_ + colT) * 640;

  for (int step = 0; step < 20; ++step){
    int kc = step * 32;
    #pragma unroll
    for (int h = 0; h < 2; ++h){
      int q = 2 * wv + h;
      gl_lds16(aBase + (size_t)(16 * q + r0) * 640 + kc + c0, &As[q * 512]);
      gl_lds16(bBase + (size_t)(16 * q + r0) * 640 + kc + c0, &Bs[q * 512]);
    }
    __syncthreads();
    bf16x8 af[4], bfr[4];
    #pragma unroll
    for (int i = 0; i < 4; ++i)
      af[i] = *(const bf16x8*)&As[(mBase + i * 16 + lr) * 32 + quad * 8];
    #pragma unroll
    for (int j = 0; j < 4; ++j)
      bfr[j] = *(const bf16x8*)&Bs[(nBase + j * 16 + lr) * 32 + quad * 8];
    #pragma unroll
    for (int i = 0; i < 4; ++i)
      #pragma unroll
      for (int j = 0; j < 4; ++j)
        acc[i][j] = __builtin_amdgcn_mfma_f32_16x16x32_bf16(af[i], bfr[j], acc[i][j], 0, 0, 0);
    __syncthreads();
  }

  float cb = cbias[0];
  bool isbf = (*flag != 0);
  #pragma unroll
  for (int i = 0; i < 4; ++i){
    #pragma unroll
    for (int r = 0; r < 4; ++r){
      int row = rowT + mBase + i * 16 + quad * 4 + r;
      float sl = slin[row] + cb;
      #pragma unroll
      for (int j = 0; j < 4; ++j){
        int t = colT + nBase + j * 16 + lr;
        float v = acc[i][j][r] + sl + tlin[b * T_ + t];
        size_t oi = (size_t)row * T_ + t;
        if (isbf) ((uint16_t*)outv)[oi] = f2bf(v);
        else      ((float*)outv)[oi] = v;
      }
    }
  }
}

// ---- phase 1: flag rows where |ps|*maxT > ZCUT (coalesced, parallel) ----
__global__ void flagrows_k(const float* __restrict__ psT, const float* __restrict__ maxT,
                           uint32_t* __restrict__ rowList, int* __restrict__ rowCnt){
  int w = blockIdx.x, b = blockIdx.y;
  int tid = threadIdx.x;
  float mt = maxT[b * W_ + w];
  const float* psc = psT + (size_t)(b * W_ + w) * S_;
  for (int s = tid; s < S_; s += 256){
    float p = psc[s];
    if (fabsf(p) * mt > ZCUT){
      int k = atomicAdd(rowCnt, 1);
      if (k < ROWCAP)
        rowList[k] = ((uint32_t)b << 19) | ((uint32_t)w << 12) | (uint32_t)s;
    }
  }
}

// ---- phase 2: one block per flagged row; exact fix CAS'd into d_out -----
__global__ __launch_bounds__(256) void fixscan_k(const float* __restrict__ psT,
        const float* __restrict__ ptT, const float* __restrict__ wint,
        const uint16_t* __restrict__ fA, const uint16_t* __restrict__ fB,
        const uint32_t* __restrict__ rowList, const int* __restrict__ rowCnt,
        const int* __restrict__ flag, void* __restrict__ outv){
  int n = *rowCnt; if (n > ROWCAP) n = ROWCAP;
  bool isbf = (*flag != 0);
  int tid = threadIdx.x;
  for (int job = blockIdx.x; job < n; job += gridDim.x){
    uint32_t pk = rowList[job];
    int b = (int)(pk >> 19), w = (int)((pk >> 12) & 127u), s = (int)(pk & 4095u);
    float wi = wint[w];
    float p = psT[(size_t)(b * W_ + w) * S_ + s];
    const float* ptc = ptT + (size_t)(b * W_ + w) * T_;
    const uint16_t* fa = fA + ((size_t)b * S_ + s) * 640 + w;
    float a0 = bf2f(fa[0]),   a1 = bf2f(fa[128]), a2 = bf2f(fa[256]);
    float a3 = bf2f(fa[384]), a4 = bf2f(fa[512]);
    for (int t = tid; t < T_; t += 256){
      float q = ptc[t];
      float z = p * q;
      if (fabsf(z) > ZCUT){
        const uint16_t* fb = fB + ((size_t)b * T_ + t) * 640 + w;
        float dot = a0 * bf2f(fb[0]) + a1 * bf2f(fb[128]) + a2 * bf2f(fb[256])
                  + a3 * bf2f(fb[384]) + a4 * bf2f(fb[512]);
        float sil = z / (1.0f + __expf(-z));
        float corr = wi * sil - dot - A0C * wi;
        size_t idx = ((size_t)b * S_ + s) * T_ + t;
        if (isbf){
          uint32_t* wp = (uint32_t*)outv + (idx >> 1);
          bool hi = (idx & 1u) != 0;
          uint32_t assumed, old = *wp;
          do {
            assumed = old;
            uint16_t h = hi ? (uint16_t)(assumed >> 16) : (uint16_t)(assumed & 0xFFFFu);
            uint16_t nh = f2bf(bf2f(h) + corr);
            uint32_t nw = hi ? ((assumed & 0x0000FFFFu) | ((uint32_t)nh << 16))
                             : ((assumed & 0xFFFF0000u) | (uint32_t)nh);
            old = atomicCAS(wp, assumed, nw);
          } while (old != assumed);
        } else {
          atomicAdd((float*)outv + idx, corr);
        }
      }
    }
  }
}

extern "C" void kernel_launch(void* const* d_in, const int* in_sizes, int n_in,
                              void* d_out, int out_size, void* d_ws, size_t ws_size,
                              hipStream_t stream){
  char* ws = (char*)d_ws;
  size_t off = 0;
  auto alloc = [&](size_t bytes)->char*{
    char* p = ws + off; off += (bytes + 255) & ~(size_t)255; return p;
  };
  int*      flag = (int*)     alloc(4);
  float*    srcf = (float*)   alloc((size_t)B_*S_*D_*4);
  float*    tgtf = (float*)   alloc((size_t)B_*T_*D_*4);
  float*    Wsf  = (float*)   alloc((size_t)W_*D_*4);
  float*    Wtf  = (float*)   alloc((size_t)W_*D_*4);
  float*    wsof = (float*)   alloc(W_*4);
  float*    wtof = (float*)   alloc(W_*4);
  float*    wif  = (float*)   alloc(W_*4);
  float*    bf   = (float*)   alloc(4);
  float*    WsT  = (float*)   alloc((size_t)D_*W_*4);
  float*    WtT  = (float*)   alloc((size_t)D_*W_*4);
  float*    ps   = (float*)   alloc((size_t)B_*S_*W_*4);
  float*    pt   = (float*)   alloc((size_t)B_*T_*W_*4);
  float*    psT  = (float*)   alloc((size_t)B_*S_*W_*4);
  float*    ptT  = (float*)   alloc((size_t)B_*T_*W_*4);
  float*    slin = (float*)   alloc((size_t)B_*S_*4);
  float*    tlin = (float*)   alloc((size_t)B_*T_*4);
  float*    maxT = (float*)   alloc((size_t)B_*W_*4);
  float*    cbias= (float*)   alloc(4);
  int*      rowCnt=(int*)     alloc(4);
  uint32_t* rowList=(uint32_t*)alloc((size_t)ROWCAP*4);
  uint16_t* featA= (uint16_t*)alloc((size_t)B_*S_*640*2);
  uint16_t* featB= (uint16_t*)alloc((size_t)B_*T_*640*2);

  hipLaunchKernelGGL(detect_k, dim3(1), dim3(64), 0, stream,
                     (const uint32_t*)d_in[0], flag);
  const int nbig = B_*S_*D_;
  hipLaunchKernelGGL(convert_k, dim3(2048), dim3(256), 0, stream, d_in[0], srcf, nbig, flag);
  hipLaunchKernelGGL(convert_k, dim3(2048), dim3(256), 0, stream, d_in[1], tgtf, nbig, flag);
  hipLaunchKernelGGL(convert_k, dim3(256),  dim3(256), 0, stream, d_in[2], Wsf, W_*D_, flag);
  hipLaunchKernelGGL(convert_k, dim3(256),  dim3(256), 0, stream, d_in[3], Wtf, W_*D_, flag);
  hipLaunchKernelGGL(convert_k, dim3(1),    dim3(256), 0, stream, d_in[4], wsof, W_, flag);
  hipLaunchKernelGGL(convert_k, dim3(1),    dim3(256), 0, stream, d_in[5], wtof, W_, flag);
  hipLaunchKernelGGL(convert_k, dim3(1),    dim3(256), 0, stream, d_in[6], wif, W_, flag);
  hipLaunchKernelGGL(convert_k, dim3(1),    dim3(256), 0, stream, d_in[7], bf, 1, flag);
  hipLaunchKernelGGL(transpose_k, dim3(2), dim3(256), 0, stream, Wsf, Wtf, WsT, WtT);
  hipLaunchKernelGGL(proj_k, dim3(B_*S_/32), dim3(256), 0, stream, srcf, WsT, wsof, ps, slin);
  hipLaunchKernelGGL(proj_k, dim3(B_*T_/32), dim3(256), 0, stream, tgtf, WtT, wtof, pt, tlin);
  hipLaunchKernelGGL(transposeP_k, dim3(2, B_*S_/64, 2), dim3(256), 0, stream,
                     ps, pt, psT, ptT);
  hipLaunchKernelGGL(cbias_k, dim3(1), dim3(64), 0, stream, wif, bf, cbias, rowCnt);
  hipLaunchKernelGGL(maxT_k, dim3(B_*W_), dim3(256), 0, stream, ptT, maxT);
  hipLaunchKernelGGL(featA_k, dim3(B_*S_*W_/256), dim3(256), 0, stream, ps, wif, featA);
  hipLaunchKernelGGL(featB_k, dim3(B_*T_*W_/256), dim3(256), 0, stream, pt, featB);
  hipLaunchKernelGGL(gemm_k, dim3(T_/128, B_*S_/128), dim3(256), 0, stream,
                     featA, featB, slin, tlin, cbias, flag, d_out);
  hipLaunchKernelGGL(flagrows_k, dim3(W_, B_), dim3(256), 0, stream,
                     psT, maxT, rowList, rowCnt);
  hipLaunchKernelGGL(fixscan_k, dim3(2048), dim3(256), 0, stream,
                     psT, ptT, wif, featA, featB, rowList, rowCnt, flag, d_out);
}